// Round 13
// baseline (2293.916 us; speedup 1.0000x reference)
//
#include <hip/hip_runtime.h>
#include <hip/hip_bf16.h>
#include <cstddef>

#define BATCH 16
#define TSTEPS 128
#define MSLOTS 512
#define DIN 256
#define UNITS 256
#define ZDIM 1024
#define GROUPS 8     // batch-pair groups
#define GBLK 16      // blocks per group
#define NBLK (GROUPS*GBLK)
#define NTHR 1024

static __device__ __forceinline__ float tanhf_fast(float x) {
    float e = __expf(2.0f * x);
    return 1.0f - 2.0f / (e + 1.0f);
}
static __device__ __forceinline__ float sigmoidf_fast(float x) {
    return 1.0f / (1.0f + __expf(-x));
}
static __device__ __forceinline__ void st_agent_u(unsigned* p, unsigned v) {
    __hip_atomic_store(p, v, __ATOMIC_RELAXED, __HIP_MEMORY_SCOPE_AGENT);
}
static __device__ __forceinline__ unsigned ld_agent_u(const unsigned* p) {
    return __hip_atomic_load(p, __ATOMIC_RELAXED, __HIP_MEMORY_SCOPE_AGENT);
}
// pack two f32 -> bf16 pair (rne); lo = a, hi = b
static __device__ __forceinline__ unsigned pack_bf(float a, float b) {
    unsigned ua = __float_as_uint(a); ua = (ua + 0x7fffu + ((ua >> 16) & 1u)) >> 16;
    unsigned ub = __float_as_uint(b); ub = ((ub + 0x7fffu + ((ub >> 16) & 1u)) >> 16) << 16;
    return ua | ub;
}
static __device__ __forceinline__ float bf_lo(unsigned w) { return __uint_as_float(w << 16); }
static __device__ __forceinline__ float bf_hi(unsigned w) { return __uint_as_float(w & 0xffff0000u); }

// ---------------------------------------------------------------------------
// f32 GEMM + bias: C[M][N] = A @ B + bias. 64x64 tile, 256 thr, 4x4/thread.
// ---------------------------------------------------------------------------
__global__ __launch_bounds__(256) void gemm_bias_kernel(
    const float* __restrict__ A, const float* __restrict__ B,
    const float* __restrict__ bias, float* __restrict__ C,
    int M, int N, int K)
{
    __shared__ float As[16][68];
    __shared__ float Bs[16][68];
    const int tid = threadIdx.x;
    const int bm = blockIdx.x * 64;
    const int bn = blockIdx.y * 64;
    const int tx = tid & 15, ty = tid >> 4;
    const int ar = tid >> 2, ac = (tid & 3) * 4;
    const int br = tid >> 4, bc = (tid & 15) * 4;
    float acc[4][4] = {};

    for (int k0 = 0; k0 < K; k0 += 16) {
        float4 av = *(const float4*)(A + (size_t)(bm + ar) * K + k0 + ac);
        float4 bv = *(const float4*)(B + (size_t)(k0 + br) * N + bn + bc);
        As[ac + 0][ar] = av.x; As[ac + 1][ar] = av.y;
        As[ac + 2][ar] = av.z; As[ac + 3][ar] = av.w;
        *(float4*)(&Bs[br][bc]) = bv;
        __syncthreads();
#pragma unroll
        for (int kk = 0; kk < 16; ++kk) {
            float a0 = As[kk][ty*4+0], a1 = As[kk][ty*4+1];
            float a2 = As[kk][ty*4+2], a3 = As[kk][ty*4+3];
            float b0 = Bs[kk][tx*4+0], b1 = Bs[kk][tx*4+1];
            float b2 = Bs[kk][tx*4+2], b3 = Bs[kk][tx*4+3];
            acc[0][0]+=a0*b0; acc[0][1]+=a0*b1; acc[0][2]+=a0*b2; acc[0][3]+=a0*b3;
            acc[1][0]+=a1*b0; acc[1][1]+=a1*b1; acc[1][2]+=a1*b2; acc[1][3]+=a1*b3;
            acc[2][0]+=a2*b0; acc[2][1]+=a2*b1; acc[2][2]+=a2*b2; acc[2][3]+=a2*b3;
            acc[3][0]+=a3*b0; acc[3][1]+=a3*b1; acc[3][2]+=a3*b2; acc[3][3]+=a3*b3;
        }
        __syncthreads();
    }
#pragma unroll
    for (int i = 0; i < 4; ++i)
#pragma unroll
        for (int j = 0; j < 4; ++j) {
            int cn = bn + tx * 4 + j;
            C[(size_t)(bm + ty * 4 + i) * N + cn] = acc[i][j] + bias[cn];
        }
}

// ---------------------------------------------------------------------------
// GEMM, no bias, bf16 output, per-batch TRANSPOSED store: CT[b][n][m] ushort.
// A rows are batch-major (512 rows per batch). Used for AW2 = attended @ W2.
// ---------------------------------------------------------------------------
__global__ __launch_bounds__(256) void gemm_T_bf16_kernel(
    const float* __restrict__ A, const float* __restrict__ B,
    unsigned short* __restrict__ CT, int M, int N, int K)
{
    __shared__ float As[16][68];
    __shared__ float Bs[16][68];
    __shared__ float Ts[64][65];
    const int tid = threadIdx.x;
    const int bm = blockIdx.x * 64;
    const int bn = blockIdx.y * 64;
    const int tx = tid & 15, ty = tid >> 4;
    const int ar = tid >> 2, ac = (tid & 3) * 4;
    const int br = tid >> 4, bc = (tid & 15) * 4;
    float acc[4][4] = {};

    for (int k0 = 0; k0 < K; k0 += 16) {
        float4 av = *(const float4*)(A + (size_t)(bm + ar) * K + k0 + ac);
        float4 bv = *(const float4*)(B + (size_t)(k0 + br) * N + bn + bc);
        As[ac + 0][ar] = av.x; As[ac + 1][ar] = av.y;
        As[ac + 2][ar] = av.z; As[ac + 3][ar] = av.w;
        *(float4*)(&Bs[br][bc]) = bv;
        __syncthreads();
#pragma unroll
        for (int kk = 0; kk < 16; ++kk) {
            float a0 = As[kk][ty*4+0], a1 = As[kk][ty*4+1];
            float a2 = As[kk][ty*4+2], a3 = As[kk][ty*4+3];
            float b0 = Bs[kk][tx*4+0], b1 = Bs[kk][tx*4+1];
            float b2 = Bs[kk][tx*4+2], b3 = Bs[kk][tx*4+3];
            acc[0][0]+=a0*b0; acc[0][1]+=a0*b1; acc[0][2]+=a0*b2; acc[0][3]+=a0*b3;
            acc[1][0]+=a1*b0; acc[1][1]+=a1*b1; acc[1][2]+=a1*b2; acc[1][3]+=a1*b3;
            acc[2][0]+=a2*b0; acc[2][1]+=a2*b1; acc[2][2]+=a2*b2; acc[2][3]+=a2*b3;
            acc[3][0]+=a3*b0; acc[3][1]+=a3*b1; acc[3][2]+=a3*b2; acc[3][3]+=a3*b3;
        }
        __syncthreads();
    }
#pragma unroll
    for (int i = 0; i < 4; ++i)
#pragma unroll
        for (int j = 0; j < 4; ++j)
            Ts[tx * 4 + j][ty * 4 + i] = acc[i][j];
    __syncthreads();
    const int jr = tid >> 2, ms2 = (tid & 3) * 16;
    const int b = bm >> 9, m0 = bm & 511;
    unsigned short* dst = CT + (size_t)b * ((size_t)N * 512)
                        + (size_t)(bn + jr) * 512 + m0 + ms2;
#pragma unroll
    for (int u = 0; u < 16; ++u) {
        unsigned ua = __float_as_uint(Ts[jr][ms2 + u]);
        ua = (ua + 0x7fffu + ((ua >> 16) & 1u)) >> 16;
        dst[u] = (unsigned short)ua;
    }
}

// ---------------------------------------------------------------------------
// Persistent scan: 128 blocks = 8 groups x 16 blocks; each group serves a
// batch PAIR (2g, 2g+1). Exchange latency of one batch hides under the other
// batch's compute. Per block per batch: m-slice 32 slots, col-slice 64 cols,
// gates for own 16 units. R11's proven sentinel protocol (wave0 payload ->
// vmcnt(0) -> sentinel; few-lane poll; burst gather). Regs: wq 32 + u 16 +
// keys 8 = 56 static. AW2 both batches in LDS (2 x 64 KB).
// ---------------------------------------------------------------------------
__global__ __launch_bounds__(NTHR, 4) void rnn_persistent(
    const float* __restrict__ query_W, const float* __restrict__ query_b,
    const float* __restrict__ attn_W,  const float* __restrict__ lstm_U,
    const float* __restrict__ keys,    const float* __restrict__ pre,
    const unsigned short* __restrict__ aw2T,
    unsigned* pB, unsigned* hB, unsigned* sent,
    float* __restrict__ seq, float* __restrict__ hT, float* __restrict__ cT)
{
    const int bid = blockIdx.x;
    // group's 16 blocks share bid%8 -> presumed same XCD (perf heuristic only)
    const int grp = bid & 7, gb = bid >> 3;      // gb in [0,16)
    const int b0 = grp * 2;                      // batches b0, b0+1
    const int tid = threadIdx.x;

    __shared__ unsigned aw2L[2][256 * 64];       // 128 KB
    __shared__ __align__(16) float h_s[2][256];
    __shared__ __align__(16) float q_s[256];
    __shared__ __align__(16) float qp_s[4][256];
    __shared__ __align__(16) float p_s[1024];    // [bt][512]
    __shared__ __align__(16) float pown_s[2][32];
    __shared__ __align__(16) float zp_s[8][128];
    __shared__ __align__(16) float zhsum_s[128];
    __shared__ __align__(16) float z_s[128];
    __shared__ __align__(16) float aw_s[256];
    __shared__ __align__(16) float qb_s[256];
    __shared__ __align__(16) float red_s[16];

    // roles
    const int jq = tid & 255, kq = tid >> 8;     // q: col jq, k-quarter kq
    const int mloc = tid >> 5, jc = tid & 31;    // scores: own m (0..31), j-comb
    const int cc2 = tid & 127, ks = tid >> 7;    // z: [bt|col] cc2, slice ks(0..7)
    const int bt_z = cc2 >> 6, cc = cc2 & 63;
    const int col_own = ((cc >> 4) << 8) + gb * 16 + (cc & 15);

    // ---- prologue: AW2 slices for both batches -> LDS (pairs along m) ----
    for (int i = tid; i < 2 * 256 * 64; i += NTHR) {
        int bt = i >> 14, r = i & 16383;
        int pr = r >> 6, c2 = r & 63;
        int colc = ((c2 >> 4) << 8) + gb * 16 + (c2 & 15);
        aw2L[bt][r] = ((const unsigned*)(aw2T + ((size_t)(b0 + bt) * ZDIM + colc) * 512))[pr];
    }
    // Wq in registers (shared across batches)
    unsigned wq_r[32];
#pragma unroll
    for (int i = 0; i < 32; ++i)
        wq_r[i] = pack_bf(query_W[(size_t)(kq * 64 + 2 * i) * 256 + jq],
                          query_W[(size_t)(kq * 64 + 2 * i + 1) * 256 + jq]);
    // keys: own m-row per batch, pairs (jc+64i, jc+64i+32)
    unsigned keys_r[2][4];
#pragma unroll
    for (int bt = 0; bt < 2; ++bt) {
        const float* krow = keys + (size_t)((b0 + bt) * MSLOTS + gb * 32 + mloc) * 256;
#pragma unroll
        for (int i = 0; i < 4; ++i)
            keys_r[bt][i] = pack_bf(krow[jc + 64 * i], krow[jc + 64 * i + 32]);
    }
    // U k-slice for own col (shared across batches)
    unsigned u_r[16];
#pragma unroll
    for (int i = 0; i < 16; ++i)
        u_r[i] = pack_bf(lstm_U[(size_t)(ks * 32 + 2 * i) * ZDIM + col_own],
                         lstm_U[(size_t)(ks * 32 + 2 * i + 1) * ZDIM + col_own]);

    if (tid < 256) {
        aw_s[tid] = attn_W[tid];
        qb_s[tid] = query_b[tid];
        h_s[0][tid] = 0.0f;
        h_s[1][tid] = 0.0f;
    }
    float c_r = 0.0f;   // tid<32: cell state for (bt=tid>>4, unit gb*16+(tid&15))
    __syncthreads();

    unsigned* sentP0 = sent + grp * 64;
    unsigned* sentP1 = sentP0 + 16;
    unsigned* sentH0 = sentP0 + 32;
    unsigned* sentH1 = sentP0 + 48;

    for (int t = 0; t < TSTEPS; ++t) {
        const unsigned tag = (unsigned)(t + 1);

        float pre_r = 0.0f;
        if (tid < 128)
            pre_r = pre[((size_t)(b0 + bt_z) * TSTEPS + t) * ZDIM + col_own];

        // ======== A phases: q + scores + publish p, per batch ========
#pragma unroll
        for (int bt = 0; bt < 2; ++bt) {
            // q partials from registers
            {
                float qa = 0.0f;
#pragma unroll
                for (int i = 0; i < 32; ++i) {
                    float2 hv = *(const float2*)&h_s[bt][kq * 64 + 2 * i];
                    qa += hv.x * bf_lo(wq_r[i]) + hv.y * bf_hi(wq_r[i]);
                }
                qp_s[kq][jq] = qa;
            }
            __syncthreads();
            if (tid < 256)
                q_s[tid] = qb_s[tid] + qp_s[0][tid] + qp_s[1][tid]
                         + qp_s[2][tid] + qp_s[3][tid];
            __syncthreads();
            // scores + exp for own 32 m
            {
                float sacc = 0.0f;
#pragma unroll
                for (int i = 0; i < 4; ++i) {
                    int j0 = jc + 64 * i, j1 = j0 + 32;
                    unsigned kw = keys_r[bt][i];
                    sacc += aw_s[j0] * tanhf_fast(bf_lo(kw) + q_s[j0]);
                    sacc += aw_s[j1] * tanhf_fast(bf_hi(kw) + q_s[j1]);
                }
                sacc += __shfl_xor(sacc, 1);
                sacc += __shfl_xor(sacc, 2);
                sacc += __shfl_xor(sacc, 4);
                sacc += __shfl_xor(sacc, 8);
                sacc += __shfl_xor(sacc, 16);
                if (jc == 0) pown_s[bt][mloc] = __expf(sacc);  // |s|<=~13
            }
            __syncthreads();
            // publish p: wave0 payload -> vmcnt -> sentinel
            if (tid < 64) {
                if (tid < 32)
                    st_agent_u(&pB[(size_t)(b0 + bt) * 512 + gb * 32 + tid],
                               __float_as_uint(pown_s[bt][tid]));
                asm volatile("s_waitcnt vmcnt(0)" ::: "memory");
                if (tid == 0) st_agent_u(bt ? &sentP1[gb] : &sentP0[gb], tag);
            }
        }

        // ======== ZH: zh partials for both batches (hides p flight) ========
        {
            float zh = 0.0f;
#pragma unroll
            for (int i = 0; i < 16; ++i) {
                float2 hv = *(const float2*)&h_s[bt_z][ks * 32 + 2 * i];
                zh += hv.x * bf_lo(u_r[i]) + hv.y * bf_hi(u_r[i]);
            }
            zp_s[ks][cc2] = zh;
        }
        __syncthreads();
        if (tid < 128)
            zhsum_s[tid] = pre_r + zp_s[0][tid] + zp_s[1][tid] + zp_s[2][tid]
                         + zp_s[3][tid] + zp_s[4][tid] + zp_s[5][tid]
                         + zp_s[6][tid] + zp_s[7][tid];
        // poll both p sentinels in parallel lanes
        if (tid < 16) {
            if (tid != gb)
                while (ld_agent_u(&sentP0[tid]) < tag) __builtin_amdgcn_s_sleep(1);
        } else if (tid < 32) {
            if ((tid & 15) != gb)
                while (ld_agent_u(&sentP1[tid & 15]) < tag) __builtin_amdgcn_s_sleep(1);
        }
        __syncthreads();

        // ======== G: gather p both batches + denominators ========
        {
            int btg = tid >> 9, idx = tid & 511;
            float pv;
            if ((idx >> 5) == gb) pv = pown_s[btg][idx & 31];
            else pv = __uint_as_float(ld_agent_u(&pB[(size_t)(b0 + btg) * 512 + idx]));
            p_s[tid] = pv;
            float dv = pv;
            dv += __shfl_xor(dv, 1);  dv += __shfl_xor(dv, 2);  dv += __shfl_xor(dv, 4);
            dv += __shfl_xor(dv, 8);  dv += __shfl_xor(dv, 16); dv += __shfl_xor(dv, 32);
            if ((tid & 63) == 0) red_s[tid >> 6] = dv;
        }
        __syncthreads();
        float inv0, inv1;
        {
            float t0 = red_s[0] + red_s[1] + red_s[2] + red_s[3]
                     + red_s[4] + red_s[5] + red_s[6] + red_s[7];
            float t1 = red_s[8] + red_s[9] + red_s[10] + red_s[11]
                     + red_s[12] + red_s[13] + red_s[14] + red_s[15];
            inv0 = 1.0f / t0;
            inv1 = 1.0f / t1;
        }

        // ======== ZC: zc partials both batches from LDS AW2 ========
        {
            float zc = 0.0f;
#pragma unroll
            for (int i = 0; i < 32; ++i) {
                float2 pv = *(const float2*)&p_s[bt_z * 512 + ks * 64 + 2 * i];
                unsigned w = aw2L[bt_z][(ks * 32 + i) * 64 + cc];
                zc += pv.x * bf_lo(w) + pv.y * bf_hi(w);
            }
            zp_s[ks][cc2] = zc;
        }
        __syncthreads();
        if (tid < 128) {
            float zcs = zp_s[0][tid] + zp_s[1][tid] + zp_s[2][tid] + zp_s[3][tid]
                      + zp_s[4][tid] + zp_s[5][tid] + zp_s[6][tid] + zp_s[7][tid];
            z_s[tid] = zhsum_s[tid] + zcs * (bt_z ? inv1 : inv0);
        }
        __syncthreads();

        // ======== gates + state for own 16 units x 2 batches; publish h ====
        if (tid < 32) {
            int bt = tid >> 4, ul = tid & 15, base = bt * 64;
            float zi = z_s[base + ul],      zf = z_s[base + 16 + ul];
            float zg = z_s[base + 32 + ul], zo = z_s[base + 48 + ul];
            float ig = sigmoidf_fast(zi);
            float fg = sigmoidf_fast(zf);
            float gg = tanhf_fast(zg);
            float og = sigmoidf_fast(zo);
            float cn = fg * c_r + ig * gg;
            float hn = og * tanhf_fast(cn);
            c_r = cn;
            int u = gb * 16 + ul;
            h_s[bt][u] = hn;
            st_agent_u(&hB[(size_t)(b0 + bt) * 256 + u], __float_as_uint(hn));
            seq[((size_t)(b0 + bt) * TSTEPS + t) * UNITS + u] = hn;
            if (t == TSTEPS - 1) {
                hT[(b0 + bt) * UNITS + u] = hn;
                cT[(b0 + bt) * UNITS + u] = cn;
            }
        }
        if (tid < 64) {   // wave0: drain payload, then both sentinels
            asm volatile("s_waitcnt vmcnt(0)" ::: "memory");
            if (tid == 0) st_agent_u(&sentH0[gb], tag);
            if (tid == 1) st_agent_u(&sentH1[gb], tag);
        }

        // ======== poll + gather h, both batches ========
        if (tid < 16) {
            if (tid != gb)
                while (ld_agent_u(&sentH0[tid]) < tag) __builtin_amdgcn_s_sleep(1);
        } else if (tid < 32) {
            if ((tid & 15) != gb)
                while (ld_agent_u(&sentH1[tid & 15]) < tag) __builtin_amdgcn_s_sleep(1);
        }
        __syncthreads();
        if (tid < 512) {
            int bt = tid >> 8, u2 = tid & 255;
            if ((u2 >> 4) != gb)
                h_s[bt][u2] = __uint_as_float(
                    ld_agent_u(&hB[(size_t)(b0 + bt) * 256 + u2]));
        }
        __syncthreads();
    }
}

// ---------------------------------------------------------------------------
extern "C" void kernel_launch(void* const* d_in, const int* in_sizes, int n_in,
                              void* d_out, int out_size, void* d_ws, size_t ws_size,
                              hipStream_t stream)
{
    (void)in_sizes; (void)n_in; (void)out_size; (void)ws_size;
    const float* inputs   = (const float*)d_in[0];
    const float* attended = (const float*)d_in[1];
    const float* key_W    = (const float*)d_in[2];
    const float* key_b    = (const float*)d_in[3];
    const float* query_W  = (const float*)d_in[4];
    const float* query_b  = (const float*)d_in[5];
    const float* attn_W   = (const float*)d_in[6];
    const float* lstm_W   = (const float*)d_in[8];
    const float* lstm_U   = (const float*)d_in[9];
    const float* lstm_b   = (const float*)d_in[10];
    // attn_b (d_in[7]) cancels in softmax — dropped.

    float* out = (float*)d_out;
    float* seq = out;
    float* hT  = out + (size_t)BATCH * TSTEPS * UNITS;
    float* cT  = hT + BATCH * UNITS;

    float* ws = (float*)d_ws;
    float* keys = ws;                                        // 2,097,152 f
    float* pre  = keys + 2097152;                            // 2,097,152 f
    unsigned short* aw2T = (unsigned short*)(pre + 2097152); // 16*1024*512 ushort
    unsigned* pB   = (unsigned*)(aw2T + (size_t)16 * 1024 * 512); // 16*512 u32
    unsigned* hB   = pB + BATCH * 512;                            // 16*256 u32
    unsigned* sent = hB + BATCH * 256;                            // 8*64 u32

    // sentinels zeroed each launch (tags >= 1) — replay-safe
    hipMemsetAsync(sent, 0, (size_t)GROUPS * 64 * sizeof(unsigned), stream);

    // keys = attended @ key_W + key_b          (8192 x 256)
    gemm_bias_kernel<<<dim3(128, 4), 256, 0, stream>>>(
        attended, key_W, key_b, keys, 8192, 256, 256);
    // pre = inputs @ lstm_W[:256] + lstm_b     (2048 x 1024)
    gemm_bias_kernel<<<dim3(32, 16), 256, 0, stream>>>(
        inputs, lstm_W, lstm_b, pre, 2048, 1024, 256);
    // AW2^T (bf16) = (attended @ lstm_W[256:])^T per batch: [b][1024][512]
    gemm_T_bf16_kernel<<<dim3(128, 16), 256, 0, stream>>>(
        attended, lstm_W + (size_t)256 * ZDIM, aw2T, 8192, 1024, 256);

    rnn_persistent<<<dim3(NBLK), dim3(NTHR), 0, stream>>>(
        query_W, query_b, attn_W, lstm_U,
        keys, pre, aw2T, pB, hB, sent, seq, hT, cT);
}